// Round 13
// baseline (199.746 us; speedup 1.0000x reference)
//
#include <hip/hip_runtime.h>
#include <stdint.h>

typedef unsigned short u16;
typedef u16   u16x4    __attribute__((ext_vector_type(4)));
typedef u16   u16x8    __attribute__((ext_vector_type(8)));
typedef u16x8 u16x8_ma __attribute__((may_alias));
typedef __bf16 bf16x8  __attribute__((ext_vector_type(8)));
typedef float f32x4    __attribute__((ext_vector_type(4)));
typedef f32x4 f32x4_ma __attribute__((may_alias));

#define EMB    1024
#define NHEAD  16
#define HD     64
#define SEQ    2048
#define NBATCH 2
#define ROWS   (NBATCH*SEQ)   // 4096
#define TSTRIDE 132           // producer V-transpose LDS stride

__device__ __forceinline__ u16 f2b(float f) {
  uint32_t u; __builtin_memcpy(&u, &f, 4);
  u = u + 0x7fffu + ((u >> 16) & 1u);
  return (u16)(u >> 16);
}
__device__ __forceinline__ u16x8 ld8(const u16* p) { return *(const u16x8_ma*)p; }
__device__ __forceinline__ void  st8(u16* p, u16x8 v) { *(u16x8_ma*)p = v; }
__device__ __forceinline__ bf16x8 asbf(u16x8 v) {
  union { u16x8 u; bf16x8 b; } c; c.u = v; return c.b;
}
// packed f32x2 -> bf16x2 (RNE), T12 recipe (no builtin on gfx950)
__device__ __forceinline__ uint32_t cvtpk(float a, float b) {
  uint32_t r;
  asm("v_cvt_pk_bf16_f32 %0, %1, %2" : "=v"(r) : "v"(a), "v"(b));
  return r;
}
// gfx950 dual-output lane swaps (VALU pipe, replaces ds_bpermute).
__device__ __forceinline__ void pl32swap(uint32_t &a, uint32_t &b) {
  asm("v_permlane32_swap_b32 %0, %1" : "+v"(a), "+v"(b));
}
__device__ __forceinline__ void pl16swap(uint32_t &a, uint32_t &b) {
  asm("v_permlane16_swap_b32 %0, %1" : "+v"(a), "+v"(b));
}
// async global->LDS, 16B/lane; LDS dest = wave-uniform base + lane*16 (m97).
__device__ __forceinline__ void async_cp16(const u16* g, u16* l) {
  __builtin_amdgcn_global_load_lds(
      (const __attribute__((address_space(1))) void*)g,
      (__attribute__((address_space(3))) void*)l, 16, 0, 0);
}
// XCD-chunked bijective block swizzle (T1).
__device__ __forceinline__ void xcd_swz(int gx, int gy, int &bx, int &by) {
  int lin = bx + gx * by;
  int q = (gx * gy) >> 3;
  int w = (lin & 7) * q + (lin >> 3);
  bx = w % gx; by = w / gx;
}

// ---------------------------------------------------------------------------
// Fused f32 -> bf16 conversion: x (4096 blocks) + 4 weights (1024 each).
// ---------------------------------------------------------------------------
__global__ __launch_bounds__(256) void cvt_all(
    const float* __restrict__ x,
    const float* __restrict__ w0, const float* __restrict__ w1,
    const float* __restrict__ w2, const float* __restrict__ w3,
    u16* __restrict__ xd, u16* __restrict__ d0, u16* __restrict__ d1,
    u16* __restrict__ d2, u16* __restrict__ d3)
{
  int bid = blockIdx.x;
  const float* s; u16* d; int off;
  if (bid < 4096) { s = x; d = xd; off = bid; }
  else {
    int t = bid - 4096; int m = t >> 10; off = t & 1023;
    switch (m) {
      case 0: s = w0; d = d0; break;
      case 1: s = w1; d = d1; break;
      case 2: s = w2; d = d2; break;
      default: s = w3; d = d3; break;
    }
  }
  size_t i = ((size_t)off * 256 + threadIdx.x) * 4;
  f32x4 v = *(const f32x4_ma*)(s + i);
  u16x4 o;
  #pragma unroll
  for (int j = 0; j < 4; j++) o[j] = f2b(v[j]);
  *(u16x4*)(d + i) = o;
}

// ---------------------------------------------------------------------------
// 128x128 GEMM core (kept for fallback kernels), BK=64 dual 128x32 panels.
// ---------------------------------------------------------------------------
template<int AMODE>
__device__ __forceinline__ void gemm_acc_128x128(
    const u16* __restrict__ A, const u16* __restrict__ B,
    int m0, int n0, u16* As, u16* Bs, f32x4 acc[4][4])
{
  const int tid  = threadIdx.x;
  const int lane = tid & 63;
  const int wave = tid >> 6;
  const int wm   = (wave >> 1) * 64;
  const int wn   = (wave & 1) * 64;
  const int ar   = tid >> 2;        // 0..63
  const int ac   = (tid & 3) * 8;   // 0,8,16,24
  const int lm   = lane & 15;
  const int lk   = (lane >> 4) * 8;

  #pragma unroll
  for (int i = 0; i < 4; i++)
    #pragma unroll
    for (int j = 0; j < 4; j++)
      #pragma unroll
      for (int e = 0; e < 4; e++) acc[i][j][e] = 0.f;

  for (int k0 = 0; k0 < EMB; k0 += 64) {
    size_t a0[2], a1[2];
    #pragma unroll
    for (int pnl = 0; pnl < 2; pnl++) {
      int kc = k0 + pnl * 32 + ac;
      if (AMODE == 0) {
        a0[pnl] = (size_t)(m0 + ar)      * EMB + kc;
        a1[pnl] = (size_t)(m0 + ar + 64) * EMB + kc;
      } else {
        int h = kc >> 6, d = kc & 63;
        int r0 = m0 + ar, r1 = m0 + ar + 64;
        a0[pnl] = (((size_t)((r0 >> 11) * NHEAD + h)) * SEQ + (r0 & (SEQ-1))) * HD + d;
        a1[pnl] = (((size_t)((r1 >> 11) * NHEAD + h)) * SEQ + (r1 & (SEQ-1))) * HD + d;
      }
    }
    __syncthreads();
    #pragma unroll
    for (int pnl = 0; pnl < 2; pnl++) {
      const int pb = pnl * 4096;
      async_cp16(A + a0[pnl], As + pb + tid * 8);
      async_cp16(A + a1[pnl], As + pb + (tid + 256) * 8);
      async_cp16(B + (size_t)(n0 + ar)      * EMB + k0 + pnl * 32 + ac, Bs + pb + tid * 8);
      async_cp16(B + (size_t)(n0 + ar + 64) * EMB + k0 + pnl * 32 + ac, Bs + pb + (tid + 256) * 8);
    }
    __syncthreads();

    #pragma unroll
    for (int pnl = 0; pnl < 2; pnl++) {
      const int pb = pnl * 4096;
      bf16x8 af[4], bfr[4];
      #pragma unroll
      for (int i = 0; i < 4; i++)
        af[i] = asbf(ld8(As + pb + (wm + i * 16 + lm) * 32 + lk));
      #pragma unroll
      for (int j = 0; j < 4; j++)
        bfr[j] = asbf(ld8(Bs + pb + (wn + j * 16 + lm) * 32 + lk));
      #pragma unroll
      for (int i = 0; i < 4; i++)
        #pragma unroll
        for (int j = 0; j < 4; j++)
          acc[i][j] = __builtin_amdgcn_mfma_f32_16x16x32_bf16(af[i], bfr[j], acc[i][j], 0, 0, 0);
    }
  }
}

// LN epilogue for 128x128 acc (fallback kernels).
__device__ __forceinline__ void epilogue_scatter_ln(
    f32x4 acc[4][4], u16* dst, int m0, int n0, int head_base, int Hdst,
    const float* g, const float* b, int do_ln)
{
  const int lane = threadIdx.x & 63, wave = threadIdx.x >> 6;
  const int wm = (wave >> 1) * 64, wn = (wave & 1) * 64;
  const int lm = lane & 15, quad = lane >> 4;

  float gv[4], bv[4];
  #pragma unroll
  for (int j = 0; j < 4; j++) { gv[j] = g[j * 16 + lm]; bv[j] = b[j * 16 + lm]; }

  #pragma unroll
  for (int i = 0; i < 4; i++)
    #pragma unroll
    for (int r = 0; r < 4; r++) {
      float val[4];
      #pragma unroll
      for (int j = 0; j < 4; j++) val[j] = acc[i][j][r];
      if (do_ln) {
        float s = val[0] + val[1] + val[2] + val[3];
        #pragma unroll
        for (int o = 8; o >= 1; o >>= 1) s += __shfl_xor(s, o, 64);
        float mean = s * (1.f / 64.f);
        float ss = 0.f;
        #pragma unroll
        for (int j = 0; j < 4; j++) { val[j] -= mean; ss += val[j] * val[j]; }
        #pragma unroll
        for (int o = 8; o >= 1; o >>= 1) ss += __shfl_xor(ss, o, 64);
        float inv = rsqrtf(ss * (1.f / 64.f) + 1e-5f);
        #pragma unroll
        for (int j = 0; j < 4; j++) val[j] = val[j] * inv * gv[j] + bv[j];
      }
      int row = m0 + wm + i * 16 + quad * 4 + r;
      int bn = row >> 11, l = row & (SEQ - 1);
      #pragma unroll
      for (int j = 0; j < 4; j++) {
        int col = n0 + wn + j * 16 + lm;
        int hl = (col >> 6) - head_base, d = col & 63;
        dst[(((size_t)(bn * Hdst + hl)) * SEQ + l) * HD + d] = f2b(val[j]);
      }
    }
}

// V epilogue: transpose the 128x128 tile through LDS (Ts reuses dead As/Bs),
// then write V^T ([N, Hdst, 64, SEQ]) with fully coalesced 16B stores.
__device__ __forceinline__ void epilogue_transpose_v(
    f32x4 acc[4][4], u16* dst, int m0, int n0, int Hdst, u16* Ts)
{
  const int tid = threadIdx.x, lane = tid & 63, wave = tid >> 6;
  const int wm = (wave >> 1) * 64;
  const int lm = lane & 15, quad = lane >> 4;
  const int bn = m0 >> 11, l0 = m0 & (SEQ - 1);

  #pragma unroll
  for (int pass = 0; pass < 2; ++pass) {
    __syncthreads();
    if ((wave & 1) == pass) {
      #pragma unroll
      for (int i = 0; i < 4; i++)
        #pragma unroll
        for (int j = 0; j < 4; j++)
          #pragma unroll
          for (int r = 0; r < 4; r++)
            Ts[(j * 16 + lm) * TSTRIDE + wm + i * 16 + quad * 4 + r] =
                f2b(acc[i][j][r]);
    }
    __syncthreads();
    const int hl = (n0 >> 6) + pass;
    u16* base = dst + ((size_t)(bn * Hdst + hl)) * HD * SEQ + l0;
    #pragma unroll
    for (int it = 0; it < 4; ++it) {
      int e = it * 2048 + tid * 8;
      int d = e >> 7, l = e & 127;
      st8(base + (size_t)d * SEQ + l, ld8(Ts + d * TSTRIDE + l));
    }
  }
}

// ---------------------------------------------------------------------------
// Q/K projection, 64x128 tiles (gemm_out-proven loop shape): grid (8,64,2)
// = 1024 blocks = 4/CU (was 128x128 at 512 blocks = 2/CU, grid-limited —
// R8 counters showed latency-bound: MfmaUtil 14 / Occ 10 / HBM 10%).
// ---------------------------------------------------------------------------
__global__ __launch_bounds__(256) void gemm_qk(
    const u16* __restrict__ x,
    const u16* __restrict__ Wq, const u16* __restrict__ Wk,
    const float* __restrict__ gq, const float* __restrict__ bq,
    const float* __restrict__ gk, const float* __restrict__ bk,
    u16* __restrict__ qd, u16* __restrict__ kb)
{
  __shared__ __align__(16) u16 As[64 * 64];    // 2 panels of 64x32
  __shared__ __align__(16) u16 Bs[128 * 64];   // 2 panels of 128x32
  int bx = blockIdx.x, by = blockIdx.y;
  xcd_swz(8, 64, bx, by);
  const int m0 = by * 64, n0 = bx * 128;
  const u16* W; u16* dst; const float* g; const float* b;
  if (blockIdx.z == 0) { W = Wq; dst = qd; g = gq; b = bq; }
  else                 { W = Wk; dst = kb; g = gk; b = bk; }

  const int tid  = threadIdx.x;
  const int lane = tid & 63;
  const int wave = tid >> 6;
  const int wm   = (wave >> 1) * 32;
  const int wn   = (wave & 1) * 64;
  const int ar   = tid >> 2;        // 0..63
  const int ac   = (tid & 3) * 8;
  const int lm   = lane & 15;
  const int lk   = (lane >> 4) * 8;

  f32x4 acc[2][4];
  #pragma unroll
  for (int i = 0; i < 2; i++)
    #pragma unroll
    for (int j = 0; j < 4; j++)
      #pragma unroll
      for (int e = 0; e < 4; e++) acc[i][j][e] = 0.f;

  for (int k0 = 0; k0 < EMB; k0 += 64) {
    __syncthreads();
    #pragma unroll
    for (int pnl = 0; pnl < 2; pnl++) {
      int kc = k0 + pnl * 32 + ac;
      async_cp16(x + (size_t)(m0 + ar) * EMB + kc, As + pnl * 2048 + tid * 8);
      async_cp16(W + (size_t)(n0 + ar)      * EMB + kc, Bs + pnl * 4096 + tid * 8);
      async_cp16(W + (size_t)(n0 + ar + 64) * EMB + kc, Bs + pnl * 4096 + (tid + 256) * 8);
    }
    __syncthreads();

    #pragma unroll
    for (int pnl = 0; pnl < 2; pnl++) {
      bf16x8 af[2], bfr[4];
      #pragma unroll
      for (int i = 0; i < 2; i++)
        af[i] = asbf(ld8(As + pnl * 2048 + (wm + i * 16 + lm) * 32 + lk));
      #pragma unroll
      for (int j = 0; j < 4; j++)
        bfr[j] = asbf(ld8(Bs + pnl * 4096 + (wn + j * 16 + lm) * 32 + lk));
      #pragma unroll
      for (int i = 0; i < 2; i++)
        #pragma unroll
        for (int j = 0; j < 4; j++)
          acc[i][j] = __builtin_amdgcn_mfma_f32_16x16x32_bf16(af[i], bfr[j], acc[i][j], 0, 0, 0);
    }
  }

  // LN epilogue over the wave's 64-col head span, acc[2][4].
  const int quad = lane >> 4;
  float gv[4], bv[4];
  #pragma unroll
  for (int j = 0; j < 4; j++) { gv[j] = g[j * 16 + lm]; bv[j] = b[j * 16 + lm]; }
  #pragma unroll
  for (int i = 0; i < 2; i++)
    #pragma unroll
    for (int r = 0; r < 4; r++) {
      float val[4];
      #pragma unroll
      for (int j = 0; j < 4; j++) val[j] = acc[i][j][r];
      float s = val[0] + val[1] + val[2] + val[3];
      #pragma unroll
      for (int o = 8; o >= 1; o >>= 1) s += __shfl_xor(s, o, 64);
      float mean = s * (1.f / 64.f);
      float ss = 0.f;
      #pragma unroll
      for (int j = 0; j < 4; j++) { val[j] -= mean; ss += val[j] * val[j]; }
      #pragma unroll
      for (int o = 8; o >= 1; o >>= 1) ss += __shfl_xor(ss, o, 64);
      float inv = rsqrtf(ss * (1.f / 64.f) + 1e-5f);
      #pragma unroll
      for (int j = 0; j < 4; j++) val[j] = val[j] * inv * gv[j] + bv[j];
      int row = m0 + wm + i * 16 + quad * 4 + r;
      int bn = row >> 11, l = row & (SEQ - 1);
      #pragma unroll
      for (int j = 0; j < 4; j++) {
        int col = n0 + wn + j * 16 + lm;
        int hl = col >> 6, d = col & 63;
        dst[(((size_t)(bn * NHEAD + hl)) * SEQ + l) * HD + d] = f2b(val[j]);
      }
    }
}

// V projection (transposed output): grid (8, 32), XCD-swizzled, unchanged.
__global__ __launch_bounds__(256) void gemm_v(
    const u16* __restrict__ x, const u16* __restrict__ Wv,
    u16* __restrict__ vb)
{
  __shared__ __align__(16) u16 buf[128 * 64 * 2];  // As | Bs, reused as Ts
  u16* As = buf;
  u16* Bs = buf + 128 * 64;
  int bx = blockIdx.x, by = blockIdx.y;
  xcd_swz(8, 32, bx, by);
  const int m0 = by * 128, n0 = bx * 128;
  f32x4 acc[4][4];
  gemm_acc_128x128<0>(x, Wv, m0, n0, As, Bs, acc);
  epilogue_transpose_v(acc, vb, m0, n0, NHEAD, buf);
}

// Fallback kernels for small-workspace multi-pass K/V.
__global__ __launch_bounds__(256) void gemm_q(
    const u16* __restrict__ x, const u16* __restrict__ Wq,
    const float* __restrict__ gq, const float* __restrict__ bq,
    u16* __restrict__ qd)
{
  __shared__ __align__(16) u16 As[128 * 64];
  __shared__ __align__(16) u16 Bs[128 * 64];
  int bx = blockIdx.x, by = blockIdx.y;
  xcd_swz(8, 32, bx, by);
  const int m0 = by * 128, n0 = bx * 128;
  f32x4 acc[4][4];
  gemm_acc_128x128<0>(x, Wq, m0, n0, As, Bs, acc);
  epilogue_scatter_ln(acc, qd, m0, n0, 0, NHEAD, gq, bq, 1);
}
__global__ __launch_bounds__(256) void gemm_kv(
    const u16* __restrict__ x,
    const u16* __restrict__ Wk, const u16* __restrict__ Wv,
    const float* __restrict__ gk, const float* __restrict__ bk,
    u16* __restrict__ k, u16* __restrict__ v, int head_lo, int hpp)
{
  __shared__ __align__(16) u16 buf[128 * 64 * 2];
  u16* As = buf;
  u16* Bs = buf + 128 * 64;
  int bx = blockIdx.x, by = blockIdx.y;
  xcd_swz(hpp / 2, 32, bx, by);
  const int m0 = by * 128, n0 = bx * 128;
  const u16* W = (blockIdx.z == 0 ? Wk : Wv) + (size_t)head_lo * HD * EMB;
  f32x4 acc[4][4];
  gemm_acc_128x128<0>(x, W, m0, n0, As, Bs, acc);
  if (blockIdx.z == 0)
    epilogue_scatter_ln(acc, k, m0, n0, 0, hpp, gk, bk, 1);
  else
    epilogue_transpose_v(acc, v, m0, n0, hpp, buf);
}

// ---------------------------------------------------------------------------
// Flash causal attention — R11 structure verbatim (measured best: 47.5 us,
// bank conflicts 0, LDS 32 KB). DMA-staged XOR-swizzled K/V^T tiles, XCD
// head colocation, T13 defer-max, permlane P-relayout.
// (R12's T15 pipeline was 48.5 — reverted.)
// ---------------------------------------------------------------------------
__global__ __launch_bounds__(256, 4) void attn(
    u16* qd, const u16* __restrict__ K, const u16* __restrict__ V,
    int head_lo, int hpp)
{
  __shared__ __align__(16) u16 Ks[2][64 * 64];
  __shared__ __align__(16) u16 Vt[2][64 * 64];   // V^T: rows=d, cols=key

  int p, hl, n;
  if (hpp == NHEAD) {
    const int lin = blockIdx.x + 32 * (blockIdx.y + NHEAD * blockIdx.z);
    const int xcd = lin & 7, idx = lin >> 3;
    const int slot = idx & 3, pp = idx >> 2;
    const int hi = pp >> 3, lo = pp & 7;
    p = (hi & 1) ? (hi * 8 + 7 - lo) : (hi * 8 + lo);
    const int head = xcd * 4 + slot;
    n = head >> 4; hl = head & 15;
  } else {
    hl = blockIdx.y; n = blockIdx.z;
    const int perm = (7 * blockIdx.x + (hl & 7) + 8 * n) & 31;
    p = perm ^ (31 * (hl >> 3));
  }
  const int tid = threadIdx.x, lane = tid & 63, wave = tid >> 6;
  const int lm = lane & 15, quad = lane >> 4;
  u16* Qh = qd + ((size_t)(n * NHEAD + head_lo + hl)) * SEQ * HD;
  const u16* Kh = K + ((size_t)(n * hpp + hl)) * SEQ * HD;
  const u16* Vh = V + ((size_t)(n * hpp + hl)) * HD * SEQ;   // transposed

  const int c0 = tid, c1 = tid + 256;
  const int kk0 = c0 >> 3, kd0 = ((c0 & 7) ^ (kk0 & 7)) * 8;
  const int kk1 = c1 >> 3, kd1 = ((c1 & 7) ^ (kk1 & 7)) * 8;
  const int vd0 = kk0, vg0 = kd0;
  const int vd1 = kk1, vg1 = kd1;

  const int lk = quad * 8;
  bf16x8 aq[2];
  #pragma unroll
  for (int ks = 0; ks < 2; ++ks)
    aq[ks] = asbf(ld8(Qh + (size_t)(p * 64 + wave * 16 + lm) * HD + ks * 32 + lk));

  #define STAGE(buf, t)                                                        \
    {                                                                          \
      const u16* Kt = Kh + (size_t)(t) * 64 * HD;                              \
      const u16* Vg = Vh + (size_t)(t) * 64;                                   \
      async_cp16(Kt + (size_t)kk0 * HD + kd0, &Ks[buf][0] + tid * 8);          \
      async_cp16(Kt + (size_t)kk1 * HD + kd1, &Ks[buf][0] + (tid + 256) * 8);  \
      async_cp16(Vg + (size_t)vd0 * SEQ + vg0, &Vt[buf][0] + tid * 8);         \
      async_cp16(Vg + (size_t)vd1 * SEQ + vg1, &Vt[buf][0] + (tid + 256) * 8); \
    }

  STAGE(0, 0);
  __syncthreads();   // vmcnt drained: tile 0 ready

  f32x4 oacc[4];
  #pragma unroll
  for (int j = 0; j < 4; j++)
    #pragma unroll
    for (int e = 0; e < 4; e++) oacc[j][e] = 0.f;
  float m_i = -1e30f, psum = 0.f;

  const int qrow = p * 64 + wave * 16 + lm;
  const int xh = lm & 7;   // read-side swizzle term

  for (int t = 0; t <= p; ++t) {
    const int cur = t & 1;
    if (t < p) STAGE(1 - cur, t + 1);

    f32x4 s[4];
    #pragma unroll
    for (int j = 0; j < 4; j++)
      #pragma unroll
      for (int e = 0; e < 4; e++) s[j][e] = 0.f;
    __builtin_amdgcn_s_setprio(1);
    #pragma unroll
    for (int ks = 0; ks < 2; ++ks)
      #pragma unroll
      for (int j = 0; j < 4; j++) {
        bf16x8 ak = asbf(ld8(&Ks[cur][((j * 16 + lm) << 6) +
                                      (((ks * 4 + quad) ^ xh) << 3)]));
        s[j] = __builtin_amdgcn_mfma_f32_16x16x32_bf16(ak, aq[ks], s[j], 0, 0, 0);
      }
    __builtin_amdgcn_s_setprio(0);

    if (t == p) {   // causal mask on the diagonal tile
      #pragma unroll
      for (int j = 0; j < 4; j++)
        #pragma unroll
        for (int r = 0; r < 4; r++)
          if (t * 64 + j * 16 + quad * 4 + r > qrow) s[j][r] = -1e30f;
    }

    float mx = fmaxf(fmaxf(s[0][0], s[0][1]), fmaxf(s[0][2], s[0][3]));
    #pragma unroll
    for (int j = 1; j < 4; j++)
      mx = fmaxf(mx, fmaxf(fmaxf(s[j][0], s[j][1]), fmaxf(s[j][2], s[j][3])));
    mx = fmaxf(mx, __shfl_xor(mx, 16, 64));
    mx = fmaxf(mx, __shfl_xor(mx, 32, 64));

    const bool defer = __all(mx <= m_i + 8.f);
    float alpha = 1.f;
    if (!defer) {
      const float mnew = fmaxf(m_i, mx);
      alpha = __expf(m_i - mnew);
      m_i = mnew;
    }
    float part = 0.f;
    #pragma unroll
    for (int j = 0; j < 4; j++)
      #pragma unroll
      for (int r = 0; r < 4; r++) {
        float pv = __expf(s[j][r] - m_i);
        s[j][r] = pv;
        part += pv;
      }
    if (defer) {
      psum += part;
    } else {
      psum = psum * alpha + part;
      float ar_[4];
      #pragma unroll
      for (int r = 0; r < 4; r++)
        ar_[r] = __shfl(alpha, (lane & 48) | (quad * 4 + r), 64);
      #pragma unroll
      for (int j = 0; j < 4; j++)
        #pragma unroll
        for (int r = 0; r < 4; r++) oacc[j][r] *= ar_[r];
    }

    uint32_t u[8];
    #pragma unroll
    for (int j = 0; j < 4; j++) {
      u[2 * j]     = cvtpk(s[j][0], s[j][1]);
      u[2 * j + 1] = cvtpk(s[j][2], s[j][3]);
    }

    __builtin_amdgcn_s_setprio(1);
    #pragma unroll
    for (int ks = 0; ks < 2; ++ks) {
      uint32_t a0 = u[ks * 4 + 0], a1 = u[ks * 4 + 1];
      uint32_t a2 = u[ks * 4 + 2], a3 = u[ks * 4 + 3];
      pl32swap(a0, a2);
      pl16swap(a0, a2);   // a0=w0, a2=w2
      pl32swap(a1, a3);
      pl16swap(a1, a3);   // a1=w1, a3=w3
      union { uint32_t w[4]; bf16x8 v; } cv;
      cv.w[0] = a0; cv.w[1] = a1; cv.w[2] = a2; cv.w[3] = a3;
      bf16x8 ap = cv.v;
      #pragma unroll
      for (int j = 0; j < 4; j++) {
        bf16x8 bv = asbf(ld8(&Vt[cur][((j * 16 + lm) << 6) +
                                      (((ks * 4 + quad) ^ xh) << 3)]));
        oacc[j] = __builtin_amdgcn_mfma_f32_16x16x32_bf16(ap, bv, oacc[j], 0, 0, 0);
      }
    }
    __builtin_amdgcn_s_setprio(0);
    __syncthreads();   // dbuf swap + vmcnt drain (next tile landed)
  }
  #undef STAGE

  float s_ = psum;
  s_ += __shfl_xor(s_, 16, 64);
  s_ += __shfl_xor(s_, 32, 64);
  const float inv = 1.0f / s_;
  float ir_[4];
  #pragma unroll
  for (int r = 0; r < 4; r++)
    ir_[r] = __shfl(inv, (lane & 48) | (quad * 4 + r), 64);
  #pragma unroll
  for (int r = 0; r < 4; r++) {
    const int row = p * 64 + wave * 16 + quad * 4 + r;
    #pragma unroll
    for (int j = 0; j < 4; j++)
      Qh[(size_t)row * HD + j * 16 + lm] = f2b(oacc[j][r] * ir_[r]);
  }
}

// ---------------------------------------------------------------------------
// Output projection, 64x64 tiles, BK=64 dual-panel: grid (16, 64) = 1024
// blocks = 4/CU (was 64x128 at 512 = 2/CU, latency-bound).
// d_out(f32) = ao @ Wo^T + bo ; ao in [N,16,L,64] bf16.
// ---------------------------------------------------------------------------
__global__ __launch_bounds__(256) void gemm_out(
    const u16* __restrict__ ao, const u16* __restrict__ Wo,
    const float* __restrict__ bo, float* __restrict__ out)
{
  __shared__ __align__(16) u16 As[64 * 64];    // 2 panels of 64x32
  __shared__ __align__(16) u16 Bs[64 * 64];    // 2 panels of 64x32
  int bx = blockIdx.x, by = blockIdx.y;
  xcd_swz(16, 64, bx, by);
  const int m0 = by * 64, n0 = bx * 64;
  const int tid  = threadIdx.x;
  const int lane = tid & 63;
  const int wave = tid >> 6;
  const int wm   = (wave >> 1) * 32;
  const int wn   = (wave & 1) * 32;
  const int ar   = tid >> 2;        // 0..63
  const int ac   = (tid & 3) * 8;
  const int lm   = lane & 15;
  const int lk   = (lane >> 4) * 8;

  f32x4 acc[2][2];
  #pragma unroll
  for (int i = 0; i < 2; i++)
    #pragma unroll
    for (int j = 0; j < 2; j++)
      #pragma unroll
      for (int e = 0; e < 4; e++) acc[i][j][e] = 0.f;

  for (int k0 = 0; k0 < EMB; k0 += 64) {
    size_t aoff[2];
    #pragma unroll
    for (int pnl = 0; pnl < 2; pnl++) {
      int kc = k0 + pnl * 32 + ac, h = kc >> 6, d = kc & 63;
      int r0 = m0 + ar;
      aoff[pnl] = (((size_t)((r0 >> 11) * NHEAD + h)) * SEQ + (r0 & (SEQ-1))) * HD + d;
    }
    __syncthreads();
    #pragma unroll
    for (int pnl = 0; pnl < 2; pnl++) {
      async_cp16(ao + aoff[pnl], As + pnl * 2048 + tid * 8);
      async_cp16(Wo + (size_t)(n0 + ar) * EMB + k0 + pnl * 32 + ac, Bs + pnl * 2048 + tid * 8);
    }
    __syncthreads();

    #pragma unroll
    for (int pnl = 0; pnl < 2; pnl++) {
      bf16x8 af[2], bfr[2];
      #pragma unroll
      for (int i = 0; i < 2; i++)
        af[i] = asbf(ld8(As + pnl * 2048 + (wm + i * 16 + lm) * 32 + lk));
      #pragma unroll
      for (int j = 0; j < 2; j++)
        bfr[j] = asbf(ld8(Bs + pnl * 2048 + (wn + j * 16 + lm) * 32 + lk));
      #pragma unroll
      for (int i = 0; i < 2; i++)
        #pragma unroll
        for (int j = 0; j < 2; j++)
          acc[i][j] = __builtin_amdgcn_mfma_f32_16x16x32_bf16(af[i], bfr[j], acc[i][j], 0, 0, 0);
    }
  }

  const int quad = lane >> 4;
  #pragma unroll
  for (int j = 0; j < 2; j++) {
    int col = n0 + wn + j * 16 + lm;
    float bias = bo[col];
    #pragma unroll
    for (int i = 0; i < 2; i++)
      #pragma unroll
      for (int r = 0; r < 4; r++) {
        int row = m0 + wm + i * 16 + quad * 4 + r;
        out[(size_t)row * EMB + col] = acc[i][j][r] + bias;
      }
  }
}

extern "C" void kernel_launch(void* const* d_in, const int* in_sizes, int n_in,
                              void* d_out, int out_size, void* d_ws, size_t ws_size,
                              hipStream_t stream)
{
  const float* xf  = (const float*)d_in[0];
  const float* Wqf = (const float*)d_in[2];
  const float* Wkf = (const float*)d_in[3];
  const float* Wvf = (const float*)d_in[4];
  const float* gq  = (const float*)d_in[5];
  const float* bq  = (const float*)d_in[6];
  const float* gk  = (const float*)d_in[7];
  const float* bk  = (const float*)d_in[8];
  const float* Wof = (const float*)d_in[9];
  const float* bo  = (const float*)d_in[10];

  const size_t MB = 1u << 20;
  u16* xb  = (u16*)d_ws;                           // 8 MiB
  u16* wqb = xb  + (size_t)ROWS * EMB;             // 2 MiB each
  u16* wkb = wqb + (size_t)EMB * EMB;
  u16* wvb = wkb + (size_t)EMB * EMB;
  u16* wob = wvb + (size_t)EMB * EMB;
  u16* kvbase = wob + (size_t)EMB * EMB;           // ws + 16 MiB

  size_t avail = (ws_size > 16 * MB) ? ws_size - 16 * MB : 2 * MB;
  int hpp = NHEAD;
  while ((size_t)hpp * MB > avail && hpp > 2) hpp >>= 1;
  const size_t kv_elems = (size_t)hpp * NBATCH * SEQ * HD;
  u16* kbuf = kvbase;
  u16* vbuf = kbuf + kv_elems;

  // Q (bf16, + in-place attn output) lives in the x input buffer (dead
  // after cvt_all). gemm_out writes f32 straight to d_out.
  u16* qd = (u16*)d_in[0];
  float* out = (float*)d_out;

  cvt_all<<<dim3(8192), 256, 0, stream>>>(xf, Wqf, Wkf, Wvf, Wof,
                                          xb, wqb, wkb, wvb, wob);
  if (hpp == NHEAD) {
    gemm_qk<<<dim3(8, 64, 2), 256, 0, stream>>>(xb, wqb, wkb,
                                                gq, bq, gk, bk, qd, kbuf);
    gemm_v<<<dim3(8, 32), 256, 0, stream>>>(xb, wvb, vbuf);
    attn<<<dim3(32, NHEAD, NBATCH), 256, 0, stream>>>(qd, kbuf, vbuf, 0, NHEAD);
  } else {
    gemm_q<<<dim3(8, 32), 256, 0, stream>>>(xb, wqb, gq, bq, qd);
    for (int g = 0; g < NHEAD / hpp; ++g) {
      gemm_kv<<<dim3(hpp / 2, 32, 2), 256, 0, stream>>>(xb, wkb, wvb, gk, bk,
                                                        kbuf, vbuf, g * hpp, hpp);
      attn<<<dim3(32, hpp, NBATCH), 256, 0, stream>>>(qd, kbuf, vbuf, g * hpp, hpp);
    }
  }
  gemm_out<<<dim3(16, 64), 256, 0, stream>>>(qd, wob, bo, out);
}

// Round 14
// 190.346 us; speedup vs baseline: 1.0494x; 1.0494x over previous
//
#include <hip/hip_runtime.h>
#include <stdint.h>

typedef unsigned short u16;
typedef u16   u16x4    __attribute__((ext_vector_type(4)));
typedef u16   u16x8    __attribute__((ext_vector_type(8)));
typedef u16x8 u16x8_ma __attribute__((may_alias));
typedef __bf16 bf16x8  __attribute__((ext_vector_type(8)));
typedef float f32x4    __attribute__((ext_vector_type(4)));
typedef f32x4 f32x4_ma __attribute__((may_alias));

#define EMB    1024
#define NHEAD  16
#define HD     64
#define SEQ    2048
#define NBATCH 2
#define ROWS   (NBATCH*SEQ)   // 4096
#define TSTRIDE 132           // producer V-transpose LDS stride

__device__ __forceinline__ u16 f2b(float f) {
  uint32_t u; __builtin_memcpy(&u, &f, 4);
  u = u + 0x7fffu + ((u >> 16) & 1u);
  return (u16)(u >> 16);
}
__device__ __forceinline__ u16x8 ld8(const u16* p) { return *(const u16x8_ma*)p; }
__device__ __forceinline__ void  st8(u16* p, u16x8 v) { *(u16x8_ma*)p = v; }
__device__ __forceinline__ bf16x8 asbf(u16x8 v) {
  union { u16x8 u; bf16x8 b; } c; c.u = v; return c.b;
}
// packed f32x2 -> bf16x2 (RNE), T12 recipe (no builtin on gfx950)
__device__ __forceinline__ uint32_t cvtpk(float a, float b) {
  uint32_t r;
  asm("v_cvt_pk_bf16_f32 %0, %1, %2" : "=v"(r) : "v"(a), "v"(b));
  return r;
}
// gfx950 dual-output lane swaps (VALU pipe, replaces ds_bpermute).
__device__ __forceinline__ void pl32swap(uint32_t &a, uint32_t &b) {
  asm("v_permlane32_swap_b32 %0, %1" : "+v"(a), "+v"(b));
}
__device__ __forceinline__ void pl16swap(uint32_t &a, uint32_t &b) {
  asm("v_permlane16_swap_b32 %0, %1" : "+v"(a), "+v"(b));
}
// async global->LDS, 16B/lane; LDS dest = wave-uniform base + lane*16 (m97).
__device__ __forceinline__ void async_cp16(const u16* g, u16* l) {
  __builtin_amdgcn_global_load_lds(
      (const __attribute__((address_space(1))) void*)g,
      (__attribute__((address_space(3))) void*)l, 16, 0, 0);
}
// XCD-chunked bijective block swizzle (T1).
__device__ __forceinline__ void xcd_swz(int gx, int gy, int &bx, int &by) {
  int lin = bx + gx * by;
  int q = (gx * gy) >> 3;
  int w = (lin & 7) * q + (lin >> 3);
  bx = w % gx; by = w / gx;
}

// ---------------------------------------------------------------------------
// Fused f32 -> bf16 conversion: x (4096 blocks) + 4 weights (1024 each).
// ---------------------------------------------------------------------------
__global__ __launch_bounds__(256) void cvt_all(
    const float* __restrict__ x,
    const float* __restrict__ w0, const float* __restrict__ w1,
    const float* __restrict__ w2, const float* __restrict__ w3,
    u16* __restrict__ xd, u16* __restrict__ d0, u16* __restrict__ d1,
    u16* __restrict__ d2, u16* __restrict__ d3)
{
  int bid = blockIdx.x;
  const float* s; u16* d; int off;
  if (bid < 4096) { s = x; d = xd; off = bid; }
  else {
    int t = bid - 4096; int m = t >> 10; off = t & 1023;
    switch (m) {
      case 0: s = w0; d = d0; break;
      case 1: s = w1; d = d1; break;
      case 2: s = w2; d = d2; break;
      default: s = w3; d = d3; break;
    }
  }
  size_t i = ((size_t)off * 256 + threadIdx.x) * 4;
  f32x4 v = *(const f32x4_ma*)(s + i);
  u16x4 o;
  #pragma unroll
  for (int j = 0; j < 4; j++) o[j] = f2b(v[j]);
  *(u16x4*)(d + i) = o;
}

// ---------------------------------------------------------------------------
// 128x128 GEMM core (kept for fallback kernels), BK=64 dual 128x32 panels.
// ---------------------------------------------------------------------------
template<int AMODE>
__device__ __forceinline__ void gemm_acc_128x128(
    const u16* __restrict__ A, const u16* __restrict__ B,
    int m0, int n0, u16* As, u16* Bs, f32x4 acc[4][4])
{
  const int tid  = threadIdx.x;
  const int lane = tid & 63;
  const int wave = tid >> 6;
  const int wm   = (wave >> 1) * 64;
  const int wn   = (wave & 1) * 64;
  const int ar   = tid >> 2;        // 0..63
  const int ac   = (tid & 3) * 8;   // 0,8,16,24
  const int lm   = lane & 15;
  const int lk   = (lane >> 4) * 8;

  #pragma unroll
  for (int i = 0; i < 4; i++)
    #pragma unroll
    for (int j = 0; j < 4; j++)
      #pragma unroll
      for (int e = 0; e < 4; e++) acc[i][j][e] = 0.f;

  for (int k0 = 0; k0 < EMB; k0 += 64) {
    size_t a0[2], a1[2];
    #pragma unroll
    for (int pnl = 0; pnl < 2; pnl++) {
      int kc = k0 + pnl * 32 + ac;
      if (AMODE == 0) {
        a0[pnl] = (size_t)(m0 + ar)      * EMB + kc;
        a1[pnl] = (size_t)(m0 + ar + 64) * EMB + kc;
      } else {
        int h = kc >> 6, d = kc & 63;
        int r0 = m0 + ar, r1 = m0 + ar + 64;
        a0[pnl] = (((size_t)((r0 >> 11) * NHEAD + h)) * SEQ + (r0 & (SEQ-1))) * HD + d;
        a1[pnl] = (((size_t)((r1 >> 11) * NHEAD + h)) * SEQ + (r1 & (SEQ-1))) * HD + d;
      }
    }
    __syncthreads();
    #pragma unroll
    for (int pnl = 0; pnl < 2; pnl++) {
      const int pb = pnl * 4096;
      async_cp16(A + a0[pnl], As + pb + tid * 8);
      async_cp16(A + a1[pnl], As + pb + (tid + 256) * 8);
      async_cp16(B + (size_t)(n0 + ar)      * EMB + k0 + pnl * 32 + ac, Bs + pb + tid * 8);
      async_cp16(B + (size_t)(n0 + ar + 64) * EMB + k0 + pnl * 32 + ac, Bs + pb + (tid + 256) * 8);
    }
    __syncthreads();

    #pragma unroll
    for (int pnl = 0; pnl < 2; pnl++) {
      const int pb = pnl * 4096;
      bf16x8 af[4], bfr[4];
      #pragma unroll
      for (int i = 0; i < 4; i++)
        af[i] = asbf(ld8(As + pb + (wm + i * 16 + lm) * 32 + lk));
      #pragma unroll
      for (int j = 0; j < 4; j++)
        bfr[j] = asbf(ld8(Bs + pb + (wn + j * 16 + lm) * 32 + lk));
      #pragma unroll
      for (int i = 0; i < 4; i++)
        #pragma unroll
        for (int j = 0; j < 4; j++)
          acc[i][j] = __builtin_amdgcn_mfma_f32_16x16x32_bf16(af[i], bfr[j], acc[i][j], 0, 0, 0);
    }
  }
}

// LN epilogue for 128x128 acc (fallback kernels).
__device__ __forceinline__ void epilogue_scatter_ln(
    f32x4 acc[4][4], u16* dst, int m0, int n0, int head_base, int Hdst,
    const float* g, const float* b, int do_ln)
{
  const int lane = threadIdx.x & 63, wave = threadIdx.x >> 6;
  const int wm = (wave >> 1) * 64, wn = (wave & 1) * 64;
  const int lm = lane & 15, quad = lane >> 4;

  float gv[4], bv[4];
  #pragma unroll
  for (int j = 0; j < 4; j++) { gv[j] = g[j * 16 + lm]; bv[j] = b[j * 16 + lm]; }

  #pragma unroll
  for (int i = 0; i < 4; i++)
    #pragma unroll
    for (int r = 0; r < 4; r++) {
      float val[4];
      #pragma unroll
      for (int j = 0; j < 4; j++) val[j] = acc[i][j][r];
      if (do_ln) {
        float s = val[0] + val[1] + val[2] + val[3];
        #pragma unroll
        for (int o = 8; o >= 1; o >>= 1) s += __shfl_xor(s, o, 64);
        float mean = s * (1.f / 64.f);
        float ss = 0.f;
        #pragma unroll
        for (int j = 0; j < 4; j++) { val[j] -= mean; ss += val[j] * val[j]; }
        #pragma unroll
        for (int o = 8; o >= 1; o >>= 1) ss += __shfl_xor(ss, o, 64);
        float inv = rsqrtf(ss * (1.f / 64.f) + 1e-5f);
        #pragma unroll
        for (int j = 0; j < 4; j++) val[j] = val[j] * inv * gv[j] + bv[j];
      }
      int row = m0 + wm + i * 16 + quad * 4 + r;
      int bn = row >> 11, l = row & (SEQ - 1);
      #pragma unroll
      for (int j = 0; j < 4; j++) {
        int col = n0 + wn + j * 16 + lm;
        int hl = (col >> 6) - head_base, d = col & 63;
        dst[(((size_t)(bn * Hdst + hl)) * SEQ + l) * HD + d] = f2b(val[j]);
      }
    }
}

// V epilogue for 128x128 acc (fallback kernels): transpose via LDS.
__device__ __forceinline__ void epilogue_transpose_v(
    f32x4 acc[4][4], u16* dst, int m0, int n0, int Hdst, u16* Ts)
{
  const int tid = threadIdx.x, lane = tid & 63, wave = tid >> 6;
  const int wm = (wave >> 1) * 64;
  const int lm = lane & 15, quad = lane >> 4;
  const int bn = m0 >> 11, l0 = m0 & (SEQ - 1);

  #pragma unroll
  for (int pass = 0; pass < 2; ++pass) {
    __syncthreads();
    if ((wave & 1) == pass) {
      #pragma unroll
      for (int i = 0; i < 4; i++)
        #pragma unroll
        for (int j = 0; j < 4; j++)
          #pragma unroll
          for (int r = 0; r < 4; r++)
            Ts[(j * 16 + lm) * TSTRIDE + wm + i * 16 + quad * 4 + r] =
                f2b(acc[i][j][r]);
    }
    __syncthreads();
    const int hl = (n0 >> 6) + pass;
    u16* base = dst + ((size_t)(bn * Hdst + hl)) * HD * SEQ + l0;
    #pragma unroll
    for (int it = 0; it < 4; ++it) {
      int e = it * 2048 + tid * 8;
      int d = e >> 7, l = e & 127;
      st8(base + (size_t)d * SEQ + l, ld8(Ts + d * TSTRIDE + l));
    }
  }
}

// ---------------------------------------------------------------------------
// Merged QKV projection, uniform 64x128 tiles (acc[2][4] in ALL branches —
// fixes R8's VGPR-132 merge failure): grid (8,64,3) = 1536 blocks = 6/CU of
// work at 4/CU residency. One launch replaces gemm_qk (4/CU) + gemm_v
// (256 blocks = 1/CU, the most underfilled launch) + the drain between.
// V epilogue: two 64x64 transpose passes through Ts[64][TSTRIDE] aliasing
// the dead As|Bs union (16.9 KB <= 24 KB; zero extra LDS).
// ---------------------------------------------------------------------------
__global__ __launch_bounds__(256) void gemm_qkv64(
    const u16* __restrict__ x,
    const u16* __restrict__ Wq, const u16* __restrict__ Wk, const u16* __restrict__ Wv,
    const float* __restrict__ gq, const float* __restrict__ bq,
    const float* __restrict__ gk, const float* __restrict__ bk,
    u16* __restrict__ qd, u16* __restrict__ kb, u16* __restrict__ vb)
{
  __shared__ __align__(16) u16 buf[64 * 64 + 128 * 64];  // As(8KB)|Bs(16KB), Ts aliases
  u16* As = buf;
  u16* Bs = buf + 64 * 64;
  int bx = blockIdx.x, by = blockIdx.y;
  xcd_swz(8, 64, bx, by);
  const int m0 = by * 64, n0 = bx * 128;
  const u16* W = (blockIdx.z == 0) ? Wq : (blockIdx.z == 1 ? Wk : Wv);

  const int tid  = threadIdx.x;
  const int lane = tid & 63;
  const int wave = tid >> 6;
  const int wm   = (wave >> 1) * 32;
  const int wn   = (wave & 1) * 64;
  const int ar   = tid >> 2;        // 0..63
  const int ac   = (tid & 3) * 8;
  const int lm   = lane & 15;
  const int lk   = (lane >> 4) * 8;

  f32x4 acc[2][4];
  #pragma unroll
  for (int i = 0; i < 2; i++)
    #pragma unroll
    for (int j = 0; j < 4; j++)
      #pragma unroll
      for (int e = 0; e < 4; e++) acc[i][j][e] = 0.f;

  for (int k0 = 0; k0 < EMB; k0 += 64) {
    __syncthreads();
    #pragma unroll
    for (int pnl = 0; pnl < 2; pnl++) {
      int kc = k0 + pnl * 32 + ac;
      async_cp16(x + (size_t)(m0 + ar) * EMB + kc, As + pnl * 2048 + tid * 8);
      async_cp16(W + (size_t)(n0 + ar)      * EMB + kc, Bs + pnl * 4096 + tid * 8);
      async_cp16(W + (size_t)(n0 + ar + 64) * EMB + kc, Bs + pnl * 4096 + (tid + 256) * 8);
    }
    __syncthreads();

    #pragma unroll
    for (int pnl = 0; pnl < 2; pnl++) {
      bf16x8 af[2], bfr[4];
      #pragma unroll
      for (int i = 0; i < 2; i++)
        af[i] = asbf(ld8(As + pnl * 2048 + (wm + i * 16 + lm) * 32 + lk));
      #pragma unroll
      for (int j = 0; j < 4; j++)
        bfr[j] = asbf(ld8(Bs + pnl * 4096 + (wn + j * 16 + lm) * 32 + lk));
      #pragma unroll
      for (int i = 0; i < 2; i++)
        #pragma unroll
        for (int j = 0; j < 4; j++)
          acc[i][j] = __builtin_amdgcn_mfma_f32_16x16x32_bf16(af[i], bfr[j], acc[i][j], 0, 0, 0);
    }
  }

  const int quad = lane >> 4;
  if (blockIdx.z == 2) {
    // V: transpose epilogue, two 64x64 passes; Ts aliases buf.
    u16* Ts = buf;
    const int bn = m0 >> 11, l0 = m0 & (SEQ - 1);
    #pragma unroll
    for (int pass = 0; pass < 2; ++pass) {
      __syncthreads();   // buf free (main-loop / previous-pass reads done)
      if ((wave & 1) == pass) {
        #pragma unroll
        for (int i = 0; i < 2; i++)
          #pragma unroll
          for (int j = 0; j < 4; j++)
            #pragma unroll
            for (int r = 0; r < 4; r++)
              Ts[(j * 16 + lm) * TSTRIDE + wm + i * 16 + quad * 4 + r] =
                  f2b(acc[i][j][r]);
      }
      __syncthreads();
      const int hl = (n0 >> 6) + pass;
      u16* base = vb + ((size_t)(bn * NHEAD + hl)) * HD * SEQ + l0;
      #pragma unroll
      for (int it = 0; it < 2; ++it) {
        int e = it * 2048 + tid * 8;
        int d = e >> 6, l = e & 63;
        st8(base + (size_t)d * SEQ + l, ld8(Ts + d * TSTRIDE + l));
      }
    }
  } else {
    // Q/K: per-head LN + scatter to [N,16,L,64].
    const float* g = (blockIdx.z == 0) ? gq : gk;
    const float* b = (blockIdx.z == 0) ? bq : bk;
    u16* dst = (blockIdx.z == 0) ? qd : kb;
    float gv[4], bv[4];
    #pragma unroll
    for (int j = 0; j < 4; j++) { gv[j] = g[j * 16 + lm]; bv[j] = b[j * 16 + lm]; }
    #pragma unroll
    for (int i = 0; i < 2; i++)
      #pragma unroll
      for (int r = 0; r < 4; r++) {
        float val[4];
        #pragma unroll
        for (int j = 0; j < 4; j++) val[j] = acc[i][j][r];
        float s = val[0] + val[1] + val[2] + val[3];
        #pragma unroll
        for (int o = 8; o >= 1; o >>= 1) s += __shfl_xor(s, o, 64);
        float mean = s * (1.f / 64.f);
        float ss = 0.f;
        #pragma unroll
        for (int j = 0; j < 4; j++) { val[j] -= mean; ss += val[j] * val[j]; }
        #pragma unroll
        for (int o = 8; o >= 1; o >>= 1) ss += __shfl_xor(ss, o, 64);
        float inv = rsqrtf(ss * (1.f / 64.f) + 1e-5f);
        #pragma unroll
        for (int j = 0; j < 4; j++) val[j] = val[j] * inv * gv[j] + bv[j];
        int row = m0 + wm + i * 16 + quad * 4 + r;
        int bn = row >> 11, l = row & (SEQ - 1);
        #pragma unroll
        for (int j = 0; j < 4; j++) {
          int col = n0 + wn + j * 16 + lm;
          int hl = col >> 6, d = col & 63;
          dst[(((size_t)(bn * NHEAD + hl)) * SEQ + l) * HD + d] = f2b(val[j]);
        }
      }
  }
}

// Fallback kernels for small-workspace multi-pass K/V.
__global__ __launch_bounds__(256) void gemm_q(
    const u16* __restrict__ x, const u16* __restrict__ Wq,
    const float* __restrict__ gq, const float* __restrict__ bq,
    u16* __restrict__ qd)
{
  __shared__ __align__(16) u16 As[128 * 64];
  __shared__ __align__(16) u16 Bs[128 * 64];
  int bx = blockIdx.x, by = blockIdx.y;
  xcd_swz(8, 32, bx, by);
  const int m0 = by * 128, n0 = bx * 128;
  f32x4 acc[4][4];
  gemm_acc_128x128<0>(x, Wq, m0, n0, As, Bs, acc);
  epilogue_scatter_ln(acc, qd, m0, n0, 0, NHEAD, gq, bq, 1);
}
__global__ __launch_bounds__(256) void gemm_kv(
    const u16* __restrict__ x,
    const u16* __restrict__ Wk, const u16* __restrict__ Wv,
    const float* __restrict__ gk, const float* __restrict__ bk,
    u16* __restrict__ k, u16* __restrict__ v, int head_lo, int hpp)
{
  __shared__ __align__(16) u16 buf[128 * 64 * 2];
  u16* As = buf;
  u16* Bs = buf + 128 * 64;
  int bx = blockIdx.x, by = blockIdx.y;
  xcd_swz(hpp / 2, 32, bx, by);
  const int m0 = by * 128, n0 = bx * 128;
  const u16* W = (blockIdx.z == 0 ? Wk : Wv) + (size_t)head_lo * HD * EMB;
  f32x4 acc[4][4];
  gemm_acc_128x128<0>(x, W, m0, n0, As, Bs, acc);
  if (blockIdx.z == 0)
    epilogue_scatter_ln(acc, k, m0, n0, 0, hpp, gk, bk, 1);
  else
    epilogue_transpose_v(acc, v, m0, n0, hpp, buf);
}

// ---------------------------------------------------------------------------
// Flash causal attention — R11 structure verbatim (measured best: 47.5 us,
// bank conflicts 0, LDS 32 KB). DMA-staged XOR-swizzled K/V^T tiles, XCD
// head colocation, T13 defer-max, permlane P-relayout.
// ---------------------------------------------------------------------------
__global__ __launch_bounds__(256, 4) void attn(
    u16* qd, const u16* __restrict__ K, const u16* __restrict__ V,
    int head_lo, int hpp)
{
  __shared__ __align__(16) u16 Ks[2][64 * 64];
  __shared__ __align__(16) u16 Vt[2][64 * 64];   // V^T: rows=d, cols=key

  int p, hl, n;
  if (hpp == NHEAD) {
    const int lin = blockIdx.x + 32 * (blockIdx.y + NHEAD * blockIdx.z);
    const int xcd = lin & 7, idx = lin >> 3;
    const int slot = idx & 3, pp = idx >> 2;
    const int hi = pp >> 3, lo = pp & 7;
    p = (hi & 1) ? (hi * 8 + 7 - lo) : (hi * 8 + lo);
    const int head = xcd * 4 + slot;
    n = head >> 4; hl = head & 15;
  } else {
    hl = blockIdx.y; n = blockIdx.z;
    const int perm = (7 * blockIdx.x + (hl & 7) + 8 * n) & 31;
    p = perm ^ (31 * (hl >> 3));
  }
  const int tid = threadIdx.x, lane = tid & 63, wave = tid >> 6;
  const int lm = lane & 15, quad = lane >> 4;
  u16* Qh = qd + ((size_t)(n * NHEAD + head_lo + hl)) * SEQ * HD;
  const u16* Kh = K + ((size_t)(n * hpp + hl)) * SEQ * HD;
  const u16* Vh = V + ((size_t)(n * hpp + hl)) * HD * SEQ;   // transposed

  const int c0 = tid, c1 = tid + 256;
  const int kk0 = c0 >> 3, kd0 = ((c0 & 7) ^ (kk0 & 7)) * 8;
  const int kk1 = c1 >> 3, kd1 = ((c1 & 7) ^ (kk1 & 7)) * 8;
  const int vd0 = kk0, vg0 = kd0;
  const int vd1 = kk1, vg1 = kd1;

  const int lk = quad * 8;
  bf16x8 aq[2];
  #pragma unroll
  for (int ks = 0; ks < 2; ++ks)
    aq[ks] = asbf(ld8(Qh + (size_t)(p * 64 + wave * 16 + lm) * HD + ks * 32 + lk));

  #define STAGE(buf, t)                                                        \
    {                                                                          \
      const u16* Kt = Kh + (size_t)(t) * 64 * HD;                              \
      const u16* Vg = Vh + (size_t)(t) * 64;                                   \
      async_cp16(Kt + (size_t)kk0 * HD + kd0, &Ks[buf][0] + tid * 8);          \
      async_cp16(Kt + (size_t)kk1 * HD + kd1, &Ks[buf][0] + (tid + 256) * 8);  \
      async_cp16(Vg + (size_t)vd0 * SEQ + vg0, &Vt[buf][0] + tid * 8);         \
      async_cp16(Vg + (size_t)vd1 * SEQ + vg1, &Vt[buf][0] + (tid + 256) * 8); \
    }

  STAGE(0, 0);
  __syncthreads();   // vmcnt drained: tile 0 ready

  f32x4 oacc[4];
  #pragma unroll
  for (int j = 0; j < 4; j++)
    #pragma unroll
    for (int e = 0; e < 4; e++) oacc[j][e] = 0.f;
  float m_i = -1e30f, psum = 0.f;

  const int qrow = p * 64 + wave * 16 + lm;
  const int xh = lm & 7;   // read-side swizzle term

  for (int t = 0; t <= p; ++t) {
    const int cur = t & 1;
    if (t < p) STAGE(1 - cur, t + 1);

    f32x4 s[4];
    #pragma unroll
    for (int j = 0; j < 4; j++)
      #pragma unroll
      for (int e = 0; e < 4; e++) s[j][e] = 0.f;
    __builtin_amdgcn_s_setprio(1);
    #pragma unroll
    for (int ks = 0; ks < 2; ++ks)
      #pragma unroll
      for (int j = 0; j < 4; j++) {
        bf16x8 ak = asbf(ld8(&Ks[cur][((j * 16 + lm) << 6) +
                                      (((ks * 4 + quad) ^ xh) << 3)]));
        s[j] = __builtin_amdgcn_mfma_f32_16x16x32_bf16(ak, aq[ks], s[j], 0, 0, 0);
      }
    __builtin_amdgcn_s_setprio(0);

    if (t == p) {   // causal mask on the diagonal tile
      #pragma unroll
      for (int j = 0; j < 4; j++)
        #pragma unroll
        for (int r = 0; r < 4; r++)
          if (t * 64 + j * 16 + quad * 4 + r > qrow) s[j][r] = -1e30f;
    }

    float mx = fmaxf(fmaxf(s[0][0], s[0][1]), fmaxf(s[0][2], s[0][3]));
    #pragma unroll
    for (int j = 1; j < 4; j++)
      mx = fmaxf(mx, fmaxf(fmaxf(s[j][0], s[j][1]), fmaxf(s[j][2], s[j][3])));
    mx = fmaxf(mx, __shfl_xor(mx, 16, 64));
    mx = fmaxf(mx, __shfl_xor(mx, 32, 64));

    const bool defer = __all(mx <= m_i + 8.f);
    float alpha = 1.f;
    if (!defer) {
      const float mnew = fmaxf(m_i, mx);
      alpha = __expf(m_i - mnew);
      m_i = mnew;
    }
    float part = 0.f;
    #pragma unroll
    for (int j = 0; j < 4; j++)
      #pragma unroll
      for (int r = 0; r < 4; r++) {
        float pv = __expf(s[j][r] - m_i);
        s[j][r] = pv;
        part += pv;
      }
    if (defer) {
      psum += part;
    } else {
      psum = psum * alpha + part;
      float ar_[4];
      #pragma unroll
      for (int r = 0; r < 4; r++)
        ar_[r] = __shfl(alpha, (lane & 48) | (quad * 4 + r), 64);
      #pragma unroll
      for (int j = 0; j < 4; j++)
        #pragma unroll
        for (int r = 0; r < 4; r++) oacc[j][r] *= ar_[r];
    }

    uint32_t u[8];
    #pragma unroll
    for (int j = 0; j < 4; j++) {
      u[2 * j]     = cvtpk(s[j][0], s[j][1]);
      u[2 * j + 1] = cvtpk(s[j][2], s[j][3]);
    }

    __builtin_amdgcn_s_setprio(1);
    #pragma unroll
    for (int ks = 0; ks < 2; ++ks) {
      uint32_t a0 = u[ks * 4 + 0], a1 = u[ks * 4 + 1];
      uint32_t a2 = u[ks * 4 + 2], a3 = u[ks * 4 + 3];
      pl32swap(a0, a2);
      pl16swap(a0, a2);   // a0=w0, a2=w2
      pl32swap(a1, a3);
      pl16swap(a1, a3);   // a1=w1, a3=w3
      union { uint32_t w[4]; bf16x8 v; } cv;
      cv.w[0] = a0; cv.w[1] = a1; cv.w[2] = a2; cv.w[3] = a3;
      bf16x8 ap = cv.v;
      #pragma unroll
      for (int j = 0; j < 4; j++) {
        bf16x8 bv = asbf(ld8(&Vt[cur][((j * 16 + lm) << 6) +
                                      (((ks * 4 + quad) ^ xh) << 3)]));
        oacc[j] = __builtin_amdgcn_mfma_f32_16x16x32_bf16(ap, bv, oacc[j], 0, 0, 0);
      }
    }
    __builtin_amdgcn_s_setprio(0);
    __syncthreads();   // dbuf swap + vmcnt drain (next tile landed)
  }
  #undef STAGE

  float s_ = psum;
  s_ += __shfl_xor(s_, 16, 64);
  s_ += __shfl_xor(s_, 32, 64);
  const float inv = 1.0f / s_;
  float ir_[4];
  #pragma unroll
  for (int r = 0; r < 4; r++)
    ir_[r] = __shfl(inv, (lane & 48) | (quad * 4 + r), 64);
  #pragma unroll
  for (int r = 0; r < 4; r++) {
    const int row = p * 64 + wave * 16 + quad * 4 + r;
    #pragma unroll
    for (int j = 0; j < 4; j++)
      Qh[(size_t)row * HD + j * 16 + lm] = f2b(oacc[j][r] * ir_[r]);
  }
}

// ---------------------------------------------------------------------------
// Output projection, 64x64 tiles, BK=64 dual-panel: grid (16, 64) = 1024
// blocks = 4/CU. d_out(f32) = ao @ Wo^T + bo ; ao in [N,16,L,64] bf16.
// ---------------------------------------------------------------------------
__global__ __launch_bounds__(256) void gemm_out(
    const u16* __restrict__ ao, const u16* __restrict__ Wo,
    const float* __restrict__ bo, float* __restrict__ out)
{
  __shared__ __align__(16) u16 As[64 * 64];    // 2 panels of 64x32
  __shared__ __align__(16) u16 Bs[64 * 64];    // 2 panels of 64x32
  int bx = blockIdx.x, by = blockIdx.y;
  xcd_swz(16, 64, bx, by);
  const int m0 = by * 64, n0 = bx * 64;
  const int tid  = threadIdx.x;
  const int lane = tid & 63;
  const int wave = tid >> 6;
  const int wm   = (wave >> 1) * 32;
  const int wn   = (wave & 1) * 32;
  const int ar   = tid >> 2;        // 0..63
  const int ac   = (tid & 3) * 8;
  const int lm   = lane & 15;
  const int lk   = (lane >> 4) * 8;

  f32x4 acc[2][2];
  #pragma unroll
  for (int i = 0; i < 2; i++)
    #pragma unroll
    for (int j = 0; j < 2; j++)
      #pragma unroll
      for (int e = 0; e < 4; e++) acc[i][j][e] = 0.f;

  for (int k0 = 0; k0 < EMB; k0 += 64) {
    size_t aoff[2];
    #pragma unroll
    for (int pnl = 0; pnl < 2; pnl++) {
      int kc = k0 + pnl * 32 + ac, h = kc >> 6, d = kc & 63;
      int r0 = m0 + ar;
      aoff[pnl] = (((size_t)((r0 >> 11) * NHEAD + h)) * SEQ + (r0 & (SEQ-1))) * HD + d;
    }
    __syncthreads();
    #pragma unroll
    for (int pnl = 0; pnl < 2; pnl++) {
      async_cp16(ao + aoff[pnl], As + pnl * 2048 + tid * 8);
      async_cp16(Wo + (size_t)(n0 + ar) * EMB + k0 + pnl * 32 + ac, Bs + pnl * 2048 + tid * 8);
    }
    __syncthreads();

    #pragma unroll
    for (int pnl = 0; pnl < 2; pnl++) {
      bf16x8 af[2], bfr[2];
      #pragma unroll
      for (int i = 0; i < 2; i++)
        af[i] = asbf(ld8(As + pnl * 2048 + (wm + i * 16 + lm) * 32 + lk));
      #pragma unroll
      for (int j = 0; j < 2; j++)
        bfr[j] = asbf(ld8(Bs + pnl * 2048 + (wn + j * 16 + lm) * 32 + lk));
      #pragma unroll
      for (int i = 0; i < 2; i++)
        #pragma unroll
        for (int j = 0; j < 2; j++)
          acc[i][j] = __builtin_amdgcn_mfma_f32_16x16x32_bf16(af[i], bfr[j], acc[i][j], 0, 0, 0);
    }
  }

  const int quad = lane >> 4;
  #pragma unroll
  for (int j = 0; j < 2; j++) {
    int col = n0 + wn + j * 16 + lm;
    float bias = bo[col];
    #pragma unroll
    for (int i = 0; i < 2; i++)
      #pragma unroll
      for (int r = 0; r < 4; r++) {
        int row = m0 + wm + i * 16 + quad * 4 + r;
        out[(size_t)row * EMB + col] = acc[i][j][r] + bias;
      }
  }
}

extern "C" void kernel_launch(void* const* d_in, const int* in_sizes, int n_in,
                              void* d_out, int out_size, void* d_ws, size_t ws_size,
                              hipStream_t stream)
{
  const float* xf  = (const float*)d_in[0];
  const float* Wqf = (const float*)d_in[2];
  const float* Wkf = (const float*)d_in[3];
  const float* Wvf = (const float*)d_in[4];
  const float* gq  = (const float*)d_in[5];
  const float* bq  = (const float*)d_in[6];
  const float* gk  = (const float*)d_in[7];
  const float* bk  = (const float*)d_in[8];
  const float* Wof = (const float*)d_in[9];
  const float* bo  = (const float*)d_in[10];

  const size_t MB = 1u << 20;
  u16* xb  = (u16*)d_ws;                           // 8 MiB
  u16* wqb = xb  + (size_t)ROWS * EMB;             // 2 MiB each
  u16* wkb = wqb + (size_t)EMB * EMB;
  u16* wvb = wkb + (size_t)EMB * EMB;
  u16* wob = wvb + (size_t)EMB * EMB;
  u16* kvbase = wob + (size_t)EMB * EMB;           // ws + 16 MiB

  size_t avail = (ws_size > 16 * MB) ? ws_size - 16 * MB : 2 * MB;
  int hpp = NHEAD;
  while ((size_t)hpp * MB > avail && hpp > 2) hpp >>= 1;
  const size_t kv_elems = (size_t)hpp * NBATCH * SEQ * HD;
  u16* kbuf = kvbase;
  u16* vbuf = kbuf + kv_elems;

  // Q (bf16, + in-place attn output) lives in the x input buffer (dead
  // after cvt_all). gemm_out writes f32 straight to d_out.
  u16* qd = (u16*)d_in[0];
  float* out = (float*)d_out;

  cvt_all<<<dim3(8192), 256, 0, stream>>>(xf, Wqf, Wkf, Wvf, Wof,
                                          xb, wqb, wkb, wvb, wob);
  if (hpp == NHEAD) {
    gemm_qkv64<<<dim3(8, 64, 3), 256, 0, stream>>>(xb, wqb, wkb, wvb,
                                                   gq, bq, gk, bk,
                                                   qd, kbuf, vbuf);
    attn<<<dim3(32, NHEAD, NBATCH), 256, 0, stream>>>(qd, kbuf, vbuf, 0, NHEAD);
  } else {
    gemm_q<<<dim3(8, 32), 256, 0, stream>>>(xb, wqb, gq, bq, qd);
    for (int g = 0; g < NHEAD / hpp; ++g) {
      gemm_kv<<<dim3(hpp / 2, 32, 2), 256, 0, stream>>>(xb, wkb, wvb, gk, bk,
                                                        kbuf, vbuf, g * hpp, hpp);
      attn<<<dim3(32, hpp, NBATCH), 256, 0, stream>>>(qd, kbuf, vbuf, g * hpp, hpp);
    }
  }
  gemm_out<<<dim3(16, 64), 256, 0, stream>>>(qd, wob, bo, out);
}